// Round 17
// baseline (64.432 us; speedup 1.0000x reference)
//
#include <hip/hip_runtime.h>
#include <hip/hip_fp16.h>

typedef __bf16 bf16_t;
typedef __bf16 bf16x8 __attribute__((ext_vector_type(8)));
typedef _Float16 f16_t;
typedef _Float16 f16x8 __attribute__((ext_vector_type(8)));
typedef float  f32x4  __attribute__((ext_vector_type(4)));

#define B_ 16
#define S_ 512
#define H_ 768
#define E_ 19
#define T0 3
#define ROWS (B_*S_)
#define SCAL 2.8853900817779268f   // 2*log2(e)
#define ECLAMP_LO (-13.5f)
#define ECLAMP_HI (15.5f)

// ---- workspace layout (bytes) ----
#define WS_W_OFF  0
#define WS_W_SZ   (H_*H_*2)                 // W bf16 prescaled by SCAL
#define WS_PL_OFF (WS_W_OFF + WS_W_SZ)
#define WS_PL_SZ  (E_*H_*2)                 // pl f16 = exp2(SCAL*(L+b)) clamped
#define WS_FC_OFF (WS_PL_OFF + WS_PL_SZ)
#define WS_FC_SZ  (H_*2)                    // fc f16 (layout keep)
#define WS_PX_OFF (WS_FC_OFF + WS_FC_SZ)
#define WS_PX_SZ  (ROWS*H_*2)               // px f16 = exp2(SCAL*x) clamped
#define WS_S_OFF  (WS_PX_OFF + WS_PX_SZ)
#define WS_S_SZ   (ROWS*20*4)               // S scores f32 [row][20]
#define WS_NEED   (WS_S_OFF + WS_S_SZ)
#define WS_AB_OFF WS_NEED
#define WS_AB_SZ  (ROWS*H_*2)               // seq as bf16
#define WS_NEED2  (WS_AB_OFF + WS_AB_SZ)

__device__ __forceinline__ float clamp_e(float v) {
  return fminf(fmaxf(v, ECLAMP_LO), ECLAMP_HI);
}

// ================= prep: W -> bf16*SCAL ; pl table ; fc f16 ; seq -> bf16 ====
__global__ __launch_bounds__(256) void prep_kernel(
    const float* __restrict__ w, const float* __restrict__ lab,
    const float* __restrict__ attb, const float* __restrict__ fcw,
    const float* __restrict__ seq,
    bf16_t* __restrict__ wbf, f16_t* __restrict__ pls,
    f16_t* __restrict__ fcg, bf16_t* __restrict__ abf) {
  int t = blockIdx.x*256 + threadIdx.x;
  int i = t*8;
  if (i < H_*H_) {
    float4 u = *(const float4*)(w + i);
    float4 v = *(const float4*)(w + i + 4);
    bf16x8 b;
    b[0]=(bf16_t)(u.x*SCAL); b[1]=(bf16_t)(u.y*SCAL); b[2]=(bf16_t)(u.z*SCAL); b[3]=(bf16_t)(u.w*SCAL);
    b[4]=(bf16_t)(v.x*SCAL); b[5]=(bf16_t)(v.y*SCAL); b[6]=(bf16_t)(v.z*SCAL); b[7]=(bf16_t)(v.w*SCAL);
    *(bf16x8*)(wbf + i) = b;
  }
  if (t < E_*H_) {
    int col = t % H_;
    float e2 = clamp_e((lab[t] + attb[col]) * SCAL);
    pls[t] = (f16_t)__builtin_amdgcn_exp2f(e2);
  }
  if (t < H_) fcg[t] = (f16_t)fcw[t];
  if (i < ROWS*H_) {
    float4 u = *(const float4*)(seq + i);
    float4 v = *(const float4*)(seq + i + 4);
    bf16x8 b;
    b[0]=(bf16_t)u.x; b[1]=(bf16_t)u.y; b[2]=(bf16_t)u.z; b[3]=(bf16_t)u.w;
    b[4]=(bf16_t)v.x; b[5]=(bf16_t)v.y; b[6]=(bf16_t)v.z; b[7]=(bf16_t)v.w;
    *(bf16x8*)(abf + i) = b;
  }
}

// ================= K1: m97-style 128x128x64 GEMM -> px f16 (proven) =========
#define G_BM 128
#define G_BN 128
#define G_BK 64
#define G_NT 256
#define G_STEPS (H_/G_BK)   // 12

__global__ __launch_bounds__(G_NT, 2) void gemm_xs2(
    const bf16_t* __restrict__ abf,
    const bf16_t* __restrict__ wbf, f16_t* __restrict__ px) {
  __shared__ __align__(16) unsigned char smem[32768];   // A [0,16K) B [16K,32K)
  const int tid  = threadIdx.x;
  const int lane = tid & 63, wv = tid >> 6;
  const int bid  = blockIdx.x;
  const int wg   = (bid & 7)*48 + (bid >> 3);   // bijective, 384%8==0
  const int rt   = wg / 6, ct = wg % 6;
  const int arow0 = rt * G_BM;
  const int bcol0 = ct * G_BN;
  const int wr = wv >> 1, wc = wv & 1;
  const int ar = lane & 15, kg = lane >> 4;

  f32x4 acc[4][4] = {};

  auto stage = [&](int s) {
    const int k0 = s * G_BK;
    #pragma unroll
    for (int it = 0; it < 4; ++it) {
      int Lb  = (wv*4 + it) * 1024;        // wave-uniform LDS base
      int L   = Lb + lane*16;              // this lane's linear slot
      int row = L >> 7;                    // /128 (tile row)
      int c   = (L >> 4) & 7;              // 16B chunk within row
      int cs  = c ^ (row & 7);             // inverse swizzle on source
      const bf16_t* srcA = abf + (size_t)(arow0 + row)*H_ + k0 + cs*8;
      __builtin_amdgcn_global_load_lds(
          (const __attribute__((address_space(1))) void*)srcA,
          (__attribute__((address_space(3))) void*)(smem + Lb), 16, 0, 0);
      const bf16_t* srcB = wbf + (size_t)(bcol0 + row)*H_ + k0 + cs*8;
      __builtin_amdgcn_global_load_lds(
          (const __attribute__((address_space(1))) void*)srcB,
          (__attribute__((address_space(3))) void*)(smem + 16384 + Lb), 16, 0, 0);
    }
  };

  stage(0);
  #pragma unroll 1
  for (int s = 0; s < G_STEPS; ++s) {
    __syncthreads();                       // staging visible (vmcnt drained)
    #pragma unroll
    for (int ks = 0; ks < 2; ++ks) {
      bf16x8 af[4], bfr[4];
      #pragma unroll
      for (int mf = 0; mf < 4; ++mf) {
        int row = wr*64 + mf*16 + ar;
        int g2  = ks*4 + kg;
        af[mf] = *(const bf16x8*)(smem + row*128 + ((g2 ^ (row & 7)) << 4));
      }
      #pragma unroll
      for (int nf = 0; nf < 4; ++nf) {
        int row = wc*64 + nf*16 + ar;
        int g2  = ks*4 + kg;
        bfr[nf] = *(const bf16x8*)(smem + 16384 + row*128 + ((g2 ^ (row & 7)) << 4));
      }
      #pragma unroll
      for (int mf = 0; mf < 4; ++mf)
        #pragma unroll
        for (int nf = 0; nf < 4; ++nf)
          acc[mf][nf] = __builtin_amdgcn_mfma_f32_16x16x32_bf16(af[mf], bfr[nf], acc[mf][nf], 0,0,0);
    }
    __syncthreads();                       // all waves done reading
    if (s + 1 < G_STEPS) stage(s + 1);
  }

  // epilogue: px[row][col] = f16(exp2(clamp(acc)))   (acc = SCAL * x_attn_nob)
  #pragma unroll
  for (int mf = 0; mf < 4; ++mf) {
    int rbase = arow0 + wr*64 + mf*16 + kg*4;
    #pragma unroll
    for (int nf = 0; nf < 4; ++nf) {
      int col = bcol0 + wc*64 + nf*16 + ar;
      #pragma unroll
      for (int i = 0; i < 4; ++i) {
        float v = clamp_e(acc[mf][nf][i]);
        px[(size_t)(rbase + i)*H_ + col] = (f16_t)__builtin_amdgcn_exp2f(v);
      }
    }
  }
}

// ================= K2a: scores only -> Sg f32 =================
// 2048 blocks x 256 thr; 4 rows/block; group(g=tid/16): r=g&3, eq=g>>2
// eval pair: fc0/u + fc1/v = (fc0*v + fc1*u)/(u*v)  -> 1 rcp / 2 evals
#define K2_R   4
#define K2_PAD 1552                      // LDS row stride (bank-spread)
#define K2_SALL (K2_R*K2_PAD)            // 6208
#define K2_LDS  (K2_SALL + K2_R*20*4)    // 6528
__global__ __launch_bounds__(256, 6) void score_k(
    const f16_t* __restrict__ px, const f16_t* __restrict__ pls,
    const float* __restrict__ fcw, float* __restrict__ Sg) {
  __shared__ __align__(16) unsigned char smem[K2_LDS];
  float* Sall = (float*)(smem + K2_SALL);
  const int tid = threadIdx.x;
  const int r0  = blockIdx.x * K2_R;     // global row base

  // stage px rows (f16), padded stride
  for (int i = tid; i < K2_R*(H_/8); i += 256) {   // 384 chunks
    int row = i / 96, kv = i % 96;
    f16x8 v = *(const f16x8*)(px + (size_t)(r0 + row)*H_ + kv*8);
    *(f16x8*)(smem + row*K2_PAD + kv*16) = v;
  }
  if (tid < K2_R) Sall[tid*20 + 19] = 0.f;   // pad slot defined
  __syncthreads();

  const int g = tid >> 4, k = tid & 15;
  const int r = g & 3, eq = g >> 2;
  const f16_t* xrow = (const f16_t*)(smem + r*K2_PAD + k*96);
  const int ebase = eq*5;
  const f16_t* lbase = pls + ebase*H_ + k*48;

  float s[5] = {};
  #pragma unroll 1
  for (int c = 0; c < 6; ++c) {
    f16x8 xh = *(const f16x8*)(xrow + c*8);             // px (LDS)
    f32x4 f0 = *(const f32x4*)(fcw + k*48 + c*8);       // fc f32 (L1/L2)
    f32x4 f1 = *(const f32x4*)(fcw + k*48 + c*8 + 4);
    #pragma unroll
    for (int j = 0; j < 5; ++j) {
      if (j == 4 && eq == 3) continue;       // e=19 doesn't exist (wave-uniform)
      f16x8 lh = *(const f16x8*)(lbase + j*H_ + c*8);   // pl (L1/L2)
      #pragma unroll
      for (int p = 0; p < 4; ++p) {
        int q0 = 2*p, q1 = 2*p + 1;
        float u = (float)xh[q0] * (float)lh[q0] + 1.0f; // v_fma_mix_f32
        float v = (float)xh[q1] * (float)lh[q1] + 1.0f; // v_fma_mix_f32
        float fa = (p < 2) ? f0[q0]   : f1[q0-4];
        float fb = (p < 2) ? f0[q1]   : f1[q1-4];
        float d  = u * v;
        float n  = fmaf(fb, u, fa * v);                 // fc0*v + fc1*u
        float rr = __builtin_amdgcn_rcpf(d);            // 1 trans / 2 evals
        s[j] = fmaf(n, rr, s[j]);
      }
    }
  }
  #pragma unroll
  for (int off = 1; off < 16; off <<= 1)
    #pragma unroll
    for (int j = 0; j < 5; ++j)
      s[j] += __shfl_xor(s[j], off, 64);
  if (k == 0) {
    #pragma unroll
    for (int j = 0; j < 5; ++j) {
      int e = ebase + j;
      if (e < E_) Sall[r*20 + e] = s[j];
    }
  }
  __syncthreads();
  // coalesced S write: 4 rows x 20 contiguous f32
  if (tid < K2_R*20) Sg[(size_t)r0*20 + tid] = Sall[tid];
}

// ================= K2b: softmax + ctx + residual + keep (streaming) =========
// 2048 blocks x 192 thr; 4 rows/block; softmax identical op-sequence to R15.
__global__ __launch_bounds__(192, 8) void ctx_k(
    const float* __restrict__ Sg, const float* __restrict__ seq,
    const float* __restrict__ lab, const int* __restrict__ counts,
    float* __restrict__ out) {
  __shared__ float Pp[K2_R*20];
  const int tid = threadIdx.x;
  const int r0  = blockIdx.x * K2_R;

  if (tid < K2_R) {
    float s2[E_]; float mx = -1e30f;
    #pragma unroll
    for (int e = 0; e < E_; ++e) {
      float v = -2.0f * Sg[(size_t)(r0 + tid)*20 + e];
      s2[e] = v; mx = fmaxf(mx, v);
    }
    float ssum = 0.f;
    #pragma unroll
    for (int e = 0; e < E_; ++e) {
      float pr = __builtin_amdgcn_exp2f((s2[e] - mx) * 1.4426950408889634f);
      s2[e] = pr; ssum += pr;
    }
    float rr = __builtin_amdgcn_rcpf(ssum);
    #pragma unroll
    for (int e = 0; e < E_; ++e) Pp[tid*20 + e] = s2[e]*rr;
  }
  __syncthreads();

  // ctx + residual + keep-mask; 192 threads own one float4-col each, 4 rows
  {
    f32x4 o4[K2_R] = {};
    #pragma unroll 1
    for (int e = 0; e < E_; ++e) {
      f32x4 la = *(const f32x4*)(lab + e*H_ + tid*4);
      #pragma unroll
      for (int rr2 = 0; rr2 < K2_R; ++rr2) {
        float pv = Pp[rr2*20 + e];
        o4[rr2] += pv * la;
      }
    }
    const int batch = r0 >> 9;
    const int cnt = counts[batch];
    #pragma unroll
    for (int rr2 = 0; rr2 < K2_R; ++rr2) {
      int row = r0 + rr2;
      int sp  = row & 511;
      bool keep = (sp >= T0) && (sp < cnt + T0);
      size_t idx = (size_t)row*H_ + tid*4;
      f32x4 sv = *(const f32x4*)(seq + idx);
      f32x4 ov = keep ? sv : (sv + o4[rr2]);
      *(f32x4*)(out + idx) = ov;
    }
  }
}

// ================= fallback: round-3 fused kernel (passed) =================
#define BM 16
#define NW 6
#define NT (NW*64)
#define A_SZ   (BM*H_*2)
#define LS_OFF A_SZ
#define LS_SZ  (E_*H_*2)
#define LDS_SZ (A_SZ + LS_SZ)
#define SP_OFF 0
#define PP_OFF (NW*BM*20*4)

__global__ __launch_bounds__(NT, 3) void ner_fused(
    const float* __restrict__ seq, const float* __restrict__ lab,
    const float* __restrict__ attw, const float* __restrict__ attb,
    const float* __restrict__ fcw, const int* __restrict__ counts,
    float* __restrict__ out)
{
  __shared__ __align__(16) unsigned char smem[LDS_SZ];
  _Float16* Lsh = (_Float16*)(smem + LS_OFF);
  float* Sp = (float*)(smem + SP_OFF);
  float* Pp = (float*)(smem + PP_OFF);
  const int tid   = threadIdx.x;
  const int blk   = blockIdx.x;
  const int batch = blk >> 5;
  const int s0    = (blk & 31) * BM;
  const size_t rowbase = ((size_t)batch * S_ + s0) * H_;
  {
    const float4* src = (const float4*)(seq + rowbase);
    #pragma unroll
    for (int i = 0; i < (BM*H_/8)/NT; ++i) {
      int idx = i*NT + tid;
      int row = idx / (H_/8);
      int kv  = idx % (H_/8);
      float4 u = src[row*(H_/4) + kv*2];
      float4 v = src[row*(H_/4) + kv*2 + 1];
      bf16x8 b;
      b[0]=(bf16_t)u.x; b[1]=(bf16_t)u.y; b[2]=(bf16_t)u.z; b[3]=(bf16_t)u.w;
      b[4]=(bf16_t)v.x; b[5]=(bf16_t)v.y; b[6]=(bf16_t)v.z; b[7]=(bf16_t)v.w;
      int byte = row*(H_*2) + kv*16;
      *(bf16x8*)(smem + (byte ^ ((row & 7) << 4))) = b;
    }
  }
  for (int i = tid*4; i < E_*H_; i += NT*4) {
    int c = i % H_;
    float4 l4 = *(const float4*)(lab + i);
    float4 b4 = *(const float4*)(attb + c);
    int e = i / H_;
    #pragma unroll
    for (int j = 0; j < 4; ++j) {
      int col = c + j;
      int wv2 = col >> 7, rr = col & 127, n = rr >> 4, arr = rr & 15;
      float v = ((&l4.x)[j] + (&b4.x)[j]) * SCAL;
      Lsh[((e*NW + wv2)*16 + arr)*8 + n] = (_Float16)v;
    }
  }
  __syncthreads();
  const int lane = tid & 63;
  const int wv   = tid >> 6;
  const int ar   = lane & 15;
  const int kg   = lane >> 4;
  const int wbase = wv * (H_/NW);
  f32x4 acc[8] = {};
  {
    const int a_sw = (ar & 7) << 4;
    #pragma unroll 1
    for (int step = 0; step < H_/32; ++step) {
      int kb = step*64 + kg*16;
      bf16x8 a0 = *(const bf16x8*)(smem + ((ar*1536 + kb) ^ a_sw));
      int k = step*32 + kg*8;
      #pragma unroll
      for (int n = 0; n < 8; ++n) {
        int gcol = wbase + n*16 + ar;
        float4 u = *(const float4*)(attw + (size_t)gcol*H_ + k);
        float4 v = *(const float4*)(attw + (size_t)gcol*H_ + k + 4);
        bf16x8 bb;
        bb[0]=(bf16_t)(u.x*SCAL); bb[1]=(bf16_t)(u.y*SCAL); bb[2]=(bf16_t)(u.z*SCAL); bb[3]=(bf16_t)(u.w*SCAL);
        bb[4]=(bf16_t)(v.x*SCAL); bb[5]=(bf16_t)(v.y*SCAL); bb[6]=(bf16_t)(v.z*SCAL); bb[7]=(bf16_t)(v.w*SCAL);
        acc[n] = __builtin_amdgcn_mfma_f32_16x16x32_bf16(a0, bb, acc[n], 0,0,0);
      }
    }
  }
  __syncthreads();
  float fcv[8];
  #pragma unroll
  for (int n = 0; n < 8; ++n) fcv[n] = fcw[wbase + n*16 + ar];
  {
    const _Float16* Lw = Lsh + (wv*16 + ar)*8;
    #pragma unroll 1
    for (int e = 0; e < E_; ++e) {
      f16x8 lh = *(const f16x8*)(Lw + e*(NW*128));
      float lv[8];
      #pragma unroll
      for (int n = 0; n < 8; ++n) lv[n] = (float)lh[n];
      float s8[4] = {};
      #pragma unroll
      for (int n = 0; n < 8; ++n)
        #pragma unroll
        for (int i = 0; i < 4; ++i) {
          float t = __builtin_amdgcn_exp2f(acc[n][i] + lv[n]);
          s8[i] += fcv[n] * __builtin_amdgcn_rcpf(t + 1.0f);
        }
      #pragma unroll
      for (int off = 1; off < 16; off <<= 1)
        #pragma unroll
        for (int i = 0; i < 4; ++i)
          s8[i] += __shfl_xor(s8[i], off, 64);
      if (ar == 0) {
        #pragma unroll
        for (int i = 0; i < 4; ++i)
          Sp[(wv*BM + kg*4 + i)*20 + e] = s8[i];
      }
    }
  }
  __syncthreads();
  if (tid % 24 == 0) {
    int row = tid / 24;
    float sc2[E_];
    float mx = -1e30f;
    #pragma unroll
    for (int e = 0; e < E_; ++e) {
      float v = 0.f;
      #pragma unroll
      for (int w2 = 0; w2 < NW; ++w2) v += Sp[(w2*BM + row)*20 + e];
      sc2[e] = -2.0f * v;
      mx = fmaxf(mx, sc2[e]);
    }
    float ssum = 0.f;
    #pragma unroll
    for (int e = 0; e < E_; ++e) {
      float p = __builtin_amdgcn_exp2f((sc2[e] - mx) * 1.4426950408889634f);
      sc2[e] = p; ssum += p;
    }
    float rr = __builtin_amdgcn_rcpf(ssum);
    #pragma unroll
    for (int e = 0; e < E_; ++e) Pp[row*20 + e] = sc2[e]*rr;
  }
  __syncthreads();
  {
    const int cg = tid % 96;
    const int rq = tid / 96;
    float o[4][8] = {};
    const f32x4* L4 = (const f32x4*)lab;
    #pragma unroll 1
    for (int e = 0; e < E_; ++e) {
      f32x4 la = L4[e*(H_/4) + cg*2];
      f32x4 lb = L4[e*(H_/4) + cg*2 + 1];
      #pragma unroll
      for (int rr2 = 0; rr2 < 4; ++rr2) {
        float p = Pp[(rq*4 + rr2)*20 + e];
        o[rr2][0] += p*la[0]; o[rr2][1] += p*la[1]; o[rr2][2] += p*la[2]; o[rr2][3] += p*la[3];
        o[rr2][4] += p*lb[0]; o[rr2][5] += p*lb[1]; o[rr2][6] += p*lb[2]; o[rr2][7] += p*lb[3];
      }
    }
    const int cnt = counts[batch];
    #pragma unroll
    for (int rr2 = 0; rr2 < 4; ++rr2) {
      int row = rq*4 + rr2;
      int sp  = s0 + row;
      bool keep = (sp >= T0) && (sp < cnt + T0);
      size_t idx = rowbase + (size_t)row*H_ + cg*8;
      float4 s1 = *(const float4*)(seq + idx);
      float4 s2v = *(const float4*)(seq + idx + 4);
      float4 o1, o2;
      if (keep) { o1 = s1; o2 = s2v; }
      else {
        o1 = make_float4(s1.x + o[rr2][0], s1.y + o[rr2][1], s1.z + o[rr2][2], s1.w + o[rr2][3]);
        o2 = make_float4(s2v.x + o[rr2][4], s2v.y + o[rr2][5], s2v.z + o[rr2][6], s2v.w + o[rr2][7]);
      }
      *(float4*)(out + idx)     = o1;
      *(float4*)(out + idx + 4) = o2;
    }
  }
}

extern "C" void kernel_launch(void* const* d_in, const int* in_sizes, int n_in,
                              void* d_out, int out_size, void* d_ws, size_t ws_size,
                              hipStream_t stream) {
  const float* seq    = (const float*)d_in[0];
  const float* lab    = (const float*)d_in[1];
  const float* attw   = (const float*)d_in[2];
  const float* attb   = (const float*)d_in[3];
  const float* fcw    = (const float*)d_in[4];
  const int*   counts = (const int*)d_in[5];
  float* out = (float*)d_out;

  if (ws_size >= (size_t)WS_NEED) {
    bf16_t* wbf = (bf16_t*)((char*)d_ws + WS_W_OFF);
    f16_t*  pls = (f16_t*)((char*)d_ws + WS_PL_OFF);
    f16_t*  fcg = (f16_t*)((char*)d_ws + WS_FC_OFF);
    f16_t*  pxp = (f16_t*)((char*)d_ws + WS_PX_OFF);
    float*  Sg  = (float*)((char*)d_ws + WS_S_OFF);
    bf16_t* abf = (ws_size >= (size_t)WS_NEED2)
                ? (bf16_t*)((char*)d_ws + WS_AB_OFF)
                : (bf16_t*)d_out;
    prep_kernel<<<dim3((ROWS*H_/8 + 255)/256), dim3(256), 0, stream>>>(
        attw, lab, attb, fcw, seq, wbf, pls, fcg, abf);
    gemm_xs2<<<dim3((ROWS/G_BM)*(H_/G_BN)), dim3(G_NT), 0, stream>>>(
        abf, wbf, pxp);
    score_k<<<dim3(ROWS/K2_R), dim3(256), 0, stream>>>(
        pxp, pls, fcw, Sg);
    ctx_k<<<dim3(ROWS/K2_R), dim3(192), 0, stream>>>(
        Sg, seq, lab, counts, out);
  } else {
    ner_fused<<<dim3(ROWS/BM), dim3(NT), 0, stream>>>(seq, lab, attw, attb, fcw, counts, out);
  }
}

// Round 18
// 58.100 us; speedup vs baseline: 1.1090x; 1.1090x over previous
//
#include <hip/hip_runtime.h>
#include <hip/hip_fp16.h>

typedef __bf16 bf16_t;
typedef __bf16 bf16x8 __attribute__((ext_vector_type(8)));
typedef _Float16 f16_t;
typedef _Float16 f16x8 __attribute__((ext_vector_type(8)));
typedef float  f32x4  __attribute__((ext_vector_type(4)));

#define B_ 16
#define S_ 512
#define H_ 768
#define E_ 19
#define T0 3
#define ROWS (B_*S_)
#define SCAL 2.8853900817779268f   // 2*log2(e)
#define ECLAMP_LO (-13.5f)
#define ECLAMP_HI (15.5f)

// ---- workspace layout (bytes) ----
#define WS_W_OFF  0
#define WS_W_SZ   (H_*H_*2)                 // W bf16 prescaled by SCAL
#define WS_PL_OFF (WS_W_OFF + WS_W_SZ)
#define WS_PL_SZ  (E_*H_*2)                 // pl f16 = exp2(SCAL*(L+b)) clamped
#define WS_FC_OFF (WS_PL_OFF + WS_PL_SZ)
#define WS_FC_SZ  (H_*2)                    // fc f16 (layout keep)
#define WS_PX_OFF (WS_FC_OFF + WS_FC_SZ)
#define WS_PX_SZ  (ROWS*H_*2)               // px f16 = exp2(SCAL*x) clamped
#define WS_NEED   (WS_PX_OFF + WS_PX_SZ)
#define WS_AB_OFF WS_NEED
#define WS_AB_SZ  (ROWS*H_*2)               // seq as bf16
#define WS_NEED2  (WS_AB_OFF + WS_AB_SZ)

__device__ __forceinline__ float clamp_e(float v) {
  return fminf(fmaxf(v, ECLAMP_LO), ECLAMP_HI);
}

// ================= prep: W -> bf16*SCAL ; pl table ; fc f16 ; seq -> bf16 ====
__global__ __launch_bounds__(256) void prep_kernel(
    const float* __restrict__ w, const float* __restrict__ lab,
    const float* __restrict__ attb, const float* __restrict__ fcw,
    const float* __restrict__ seq,
    bf16_t* __restrict__ wbf, f16_t* __restrict__ pls,
    f16_t* __restrict__ fcg, bf16_t* __restrict__ abf) {
  int t = blockIdx.x*256 + threadIdx.x;
  int i = t*8;
  if (i < H_*H_) {
    float4 u = *(const float4*)(w + i);
    float4 v = *(const float4*)(w + i + 4);
    bf16x8 b;
    b[0]=(bf16_t)(u.x*SCAL); b[1]=(bf16_t)(u.y*SCAL); b[2]=(bf16_t)(u.z*SCAL); b[3]=(bf16_t)(u.w*SCAL);
    b[4]=(bf16_t)(v.x*SCAL); b[5]=(bf16_t)(v.y*SCAL); b[6]=(bf16_t)(v.z*SCAL); b[7]=(bf16_t)(v.w*SCAL);
    *(bf16x8*)(wbf + i) = b;
  }
  if (t < E_*H_) {
    int col = t % H_;
    float e2 = clamp_e((lab[t] + attb[col]) * SCAL);
    pls[t] = (f16_t)__builtin_amdgcn_exp2f(e2);
  }
  if (t < H_) fcg[t] = (f16_t)fcw[t];
  if (i < ROWS*H_) {
    float4 u = *(const float4*)(seq + i);
    float4 v = *(const float4*)(seq + i + 4);
    bf16x8 b;
    b[0]=(bf16_t)u.x; b[1]=(bf16_t)u.y; b[2]=(bf16_t)u.z; b[3]=(bf16_t)u.w;
    b[4]=(bf16_t)v.x; b[5]=(bf16_t)v.y; b[6]=(bf16_t)v.z; b[7]=(bf16_t)v.w;
    *(bf16x8*)(abf + i) = b;
  }
}

// ================= K1: m97-style 128x128x64 GEMM -> px f16 (proven) =========
#define G_BM 128
#define G_BN 128
#define G_BK 64
#define G_NT 256
#define G_STEPS (H_/G_BK)   // 12

__global__ __launch_bounds__(G_NT, 2) void gemm_xs2(
    const bf16_t* __restrict__ abf,
    const bf16_t* __restrict__ wbf, f16_t* __restrict__ px) {
  __shared__ __align__(16) unsigned char smem[32768];   // A [0,16K) B [16K,32K)
  const int tid  = threadIdx.x;
  const int lane = tid & 63, wv = tid >> 6;
  const int bid  = blockIdx.x;
  const int wg   = (bid & 7)*48 + (bid >> 3);   // bijective, 384%8==0
  const int rt   = wg / 6, ct = wg % 6;
  const int arow0 = rt * G_BM;
  const int bcol0 = ct * G_BN;
  const int wr = wv >> 1, wc = wv & 1;
  const int ar = lane & 15, kg = lane >> 4;

  f32x4 acc[4][4] = {};

  auto stage = [&](int s) {
    const int k0 = s * G_BK;
    #pragma unroll
    for (int it = 0; it < 4; ++it) {
      int Lb  = (wv*4 + it) * 1024;        // wave-uniform LDS base
      int L   = Lb + lane*16;              // this lane's linear slot
      int row = L >> 7;                    // /128 (tile row)
      int c   = (L >> 4) & 7;              // 16B chunk within row
      int cs  = c ^ (row & 7);             // inverse swizzle on source
      const bf16_t* srcA = abf + (size_t)(arow0 + row)*H_ + k0 + cs*8;
      __builtin_amdgcn_global_load_lds(
          (const __attribute__((address_space(1))) void*)srcA,
          (__attribute__((address_space(3))) void*)(smem + Lb), 16, 0, 0);
      const bf16_t* srcB = wbf + (size_t)(bcol0 + row)*H_ + k0 + cs*8;
      __builtin_amdgcn_global_load_lds(
          (const __attribute__((address_space(1))) void*)srcB,
          (__attribute__((address_space(3))) void*)(smem + 16384 + Lb), 16, 0, 0);
    }
  };

  stage(0);
  #pragma unroll 1
  for (int s = 0; s < G_STEPS; ++s) {
    __syncthreads();                       // staging visible (vmcnt drained)
    #pragma unroll
    for (int ks = 0; ks < 2; ++ks) {
      bf16x8 af[4], bfr[4];
      #pragma unroll
      for (int mf = 0; mf < 4; ++mf) {
        int row = wr*64 + mf*16 + ar;
        int g2  = ks*4 + kg;
        af[mf] = *(const bf16x8*)(smem + row*128 + ((g2 ^ (row & 7)) << 4));
      }
      #pragma unroll
      for (int nf = 0; nf < 4; ++nf) {
        int row = wc*64 + nf*16 + ar;
        int g2  = ks*4 + kg;
        bfr[nf] = *(const bf16x8*)(smem + 16384 + row*128 + ((g2 ^ (row & 7)) << 4));
      }
      #pragma unroll
      for (int mf = 0; mf < 4; ++mf)
        #pragma unroll
        for (int nf = 0; nf < 4; ++nf)
          acc[mf][nf] = __builtin_amdgcn_mfma_f32_16x16x32_bf16(af[mf], bfr[nf], acc[mf][nf], 0,0,0);
    }
    __syncthreads();                       // all waves done reading
    if (s + 1 < G_STEPS) stage(s + 1);
  }

  // epilogue: px[row][col] = f16(exp2(clamp(acc)))   (acc = SCAL * x_attn_nob)
  #pragma unroll
  for (int mf = 0; mf < 4; ++mf) {
    int rbase = arow0 + wr*64 + mf*16 + kg*4;
    #pragma unroll
    for (int nf = 0; nf < 4; ++nf) {
      int col = bcol0 + wc*64 + nf*16 + ar;
      #pragma unroll
      for (int i = 0; i < 4; ++i) {
        float v = clamp_e(acc[mf][nf][i]);
        px[(size_t)(rbase + i)*H_ + col] = (f16_t)__builtin_amdgcn_exp2f(v);
      }
    }
  }
}

// ================= K2: score + softmax + ctx (fma_mix eval, unroll-2 c-loop) =
// 2048 blocks x 256 thr; 4 rows/block; group(g=tid/16): r=g&3, eq=g>>2
// sigma(-2x_tot) = 1/(1 + px*pl); eval: u = fma_mix(px,pl,1); rcp_f32; fmac.
#define K2_R   4
#define K2_PAD 1552                      // LDS row stride (bank-spread)
#define K2_SALL (K2_R*K2_PAD)            // 6208
#define K2_PP   (K2_SALL + K2_R*20*4)    // 6528
#define K2_LDS  (K2_PP + K2_R*20*4)      // 6848
__global__ __launch_bounds__(256, 6) void score_ctx(
    const f16_t* __restrict__ px, const f16_t* __restrict__ pls,
    const float* __restrict__ fcw, const float* __restrict__ seq,
    const float* __restrict__ lab, const int* __restrict__ counts,
    float* __restrict__ out) {
  __shared__ __align__(16) unsigned char smem[K2_LDS];
  float* Sall = (float*)(smem + K2_SALL);
  float* Pp   = (float*)(smem + K2_PP);
  const int tid = threadIdx.x;
  const int r0  = blockIdx.x * K2_R;     // global row base

  // stage px rows (f16), padded stride
  for (int i = tid; i < K2_R*(H_/8); i += 256) {   // 384 chunks
    int row = i / 96, kv = i % 96;
    f16x8 v = *(const f16x8*)(px + (size_t)(r0 + row)*H_ + kv*8);
    *(f16x8*)(smem + row*K2_PAD + kv*16) = v;
  }
  __syncthreads();

  const int g = tid >> 4, k = tid & 15;
  const int r = g & 3, eq = g >> 2;
  const f16_t* xrow = (const f16_t*)(smem + r*K2_PAD + k*96);
  const int ebase = eq*5;
  const f16_t* lbase = pls + ebase*H_ + k*48;

  float s[5] = {};
  #pragma unroll 2
  for (int c = 0; c < 6; ++c) {
    f16x8 xh = *(const f16x8*)(xrow + c*8);             // px (LDS)
    f32x4 f0 = *(const f32x4*)(fcw + k*48 + c*8);       // fc f32 (L1/L2)
    f32x4 f1 = *(const f32x4*)(fcw + k*48 + c*8 + 4);
    #pragma unroll
    for (int j = 0; j < 5; ++j) {
      if (j == 4 && eq == 3) continue;       // e=19 doesn't exist (wave-uniform)
      f16x8 lh = *(const f16x8*)(lbase + j*H_ + c*8);   // pl (L1/L2)
      #pragma unroll
      for (int q = 0; q < 8; ++q) {
        float u  = (float)xh[q] * (float)lh[q] + 1.0f;  // v_fma_mix_f32
        float rr = __builtin_amdgcn_rcpf(u);            // v_rcp_f32
        float fq = (q < 4) ? f0[q] : f1[q-4];
        s[j] += fq * rr;                                // v_fmac_f32
      }
    }
  }
  #pragma unroll
  for (int off = 1; off < 16; off <<= 1)
    #pragma unroll
    for (int j = 0; j < 5; ++j)
      s[j] += __shfl_xor(s[j], off, 64);
  if (k == 0) {
    #pragma unroll
    for (int j = 0; j < 5; ++j) {
      int e = ebase + j;
      if (e < E_) Sall[r*20 + e] = s[j];
    }
  }
  __syncthreads();

  // softmax per row (logits = -2*S, const shift drops out)
  if (tid < K2_R) {
    float s2[E_]; float mx = -1e30f;
    #pragma unroll
    for (int e = 0; e < E_; ++e) {
      float v = -2.0f * Sall[tid*20 + e];
      s2[e] = v; mx = fmaxf(mx, v);
    }
    float ssum = 0.f;
    #pragma unroll
    for (int e = 0; e < E_; ++e) {
      float pr = __builtin_amdgcn_exp2f((s2[e] - mx) * 1.4426950408889634f);
      s2[e] = pr; ssum += pr;
    }
    float rr = __builtin_amdgcn_rcpf(ssum);
    #pragma unroll
    for (int e = 0; e < E_; ++e) Pp[tid*20 + e] = s2[e]*rr;
  }
  __syncthreads();

  // ctx + residual + keep-mask; 192 threads own one float4-col each, 4 rows
  if (tid < 192) {
    f32x4 o4[K2_R] = {};
    #pragma unroll 1
    for (int e = 0; e < E_; ++e) {
      f32x4 la = *(const f32x4*)(lab + e*H_ + tid*4);
      #pragma unroll
      for (int rr2 = 0; rr2 < K2_R; ++rr2) {
        float pv = Pp[rr2*20 + e];
        o4[rr2] += pv * la;
      }
    }
    const int batch = r0 >> 9;
    const int cnt = counts[batch];
    #pragma unroll
    for (int rr2 = 0; rr2 < K2_R; ++rr2) {
      int row = r0 + rr2;
      int sp  = row & 511;
      bool keep = (sp >= T0) && (sp < cnt + T0);
      size_t idx = (size_t)row*H_ + tid*4;
      f32x4 sv = *(const f32x4*)(seq + idx);
      f32x4 ov = keep ? sv : (sv + o4[rr2]);
      *(f32x4*)(out + idx) = ov;
    }
  }
}

// ================= fallback: round-3 fused kernel (passed) =================
#define BM 16
#define NW 6
#define NT (NW*64)
#define A_SZ   (BM*H_*2)
#define LS_OFF A_SZ
#define LS_SZ  (E_*H_*2)
#define LDS_SZ (A_SZ + LS_SZ)
#define SP_OFF 0
#define PP_OFF (NW*BM*20*4)

__global__ __launch_bounds__(NT, 3) void ner_fused(
    const float* __restrict__ seq, const float* __restrict__ lab,
    const float* __restrict__ attw, const float* __restrict__ attb,
    const float* __restrict__ fcw, const int* __restrict__ counts,
    float* __restrict__ out)
{
  __shared__ __align__(16) unsigned char smem[LDS_SZ];
  _Float16* Lsh = (_Float16*)(smem + LS_OFF);
  float* Sp = (float*)(smem + SP_OFF);
  float* Pp = (float*)(smem + PP_OFF);
  const int tid   = threadIdx.x;
  const int blk   = blockIdx.x;
  const int batch = blk >> 5;
  const int s0    = (blk & 31) * BM;
  const size_t rowbase = ((size_t)batch * S_ + s0) * H_;
  {
    const float4* src = (const float4*)(seq + rowbase);
    #pragma unroll
    for (int i = 0; i < (BM*H_/8)/NT; ++i) {
      int idx = i*NT + tid;
      int row = idx / (H_/8);
      int kv  = idx % (H_/8);
      float4 u = src[row*(H_/4) + kv*2];
      float4 v = src[row*(H_/4) + kv*2 + 1];
      bf16x8 b;
      b[0]=(bf16_t)u.x; b[1]=(bf16_t)u.y; b[2]=(bf16_t)u.z; b[3]=(bf16_t)u.w;
      b[4]=(bf16_t)v.x; b[5]=(bf16_t)v.y; b[6]=(bf16_t)v.z; b[7]=(bf16_t)v.w;
      int byte = row*(H_*2) + kv*16;
      *(bf16x8*)(smem + (byte ^ ((row & 7) << 4))) = b;
    }
  }
  for (int i = tid*4; i < E_*H_; i += NT*4) {
    int c = i % H_;
    float4 l4 = *(const float4*)(lab + i);
    float4 b4 = *(const float4*)(attb + c);
    int e = i / H_;
    #pragma unroll
    for (int j = 0; j < 4; ++j) {
      int col = c + j;
      int wv2 = col >> 7, rr = col & 127, n = rr >> 4, arr = rr & 15;
      float v = ((&l4.x)[j] + (&b4.x)[j]) * SCAL;
      Lsh[((e*NW + wv2)*16 + arr)*8 + n] = (_Float16)v;
    }
  }
  __syncthreads();
  const int lane = tid & 63;
  const int wv   = tid >> 6;
  const int ar   = lane & 15;
  const int kg   = lane >> 4;
  const int wbase = wv * (H_/NW);
  f32x4 acc[8] = {};
  {
    const int a_sw = (ar & 7) << 4;
    #pragma unroll 1
    for (int step = 0; step < H_/32; ++step) {
      int kb = step*64 + kg*16;
      bf16x8 a0 = *(const bf16x8*)(smem + ((ar*1536 + kb) ^ a_sw));
      int k = step*32 + kg*8;
      #pragma unroll
      for (int n = 0; n < 8; ++n) {
        int gcol = wbase + n*16 + ar;
        float4 u = *(const float4*)(attw + (size_t)gcol*H_ + k);
        float4 v = *(const float4*)(attw + (size_t)gcol*H_ + k + 4);
        bf16x8 bb;
        bb[0]=(bf16_t)(u.x*SCAL); bb[1]=(bf16_t)(u.y*SCAL); bb[2]=(bf16_t)(u.z*SCAL); bb[3]=(bf16_t)(u.w*SCAL);
        bb[4]=(bf16_t)(v.x*SCAL); bb[5]=(bf16_t)(v.y*SCAL); bb[6]=(bf16_t)(v.z*SCAL); bb[7]=(bf16_t)(v.w*SCAL);
        acc[n] = __builtin_amdgcn_mfma_f32_16x16x32_bf16(a0, bb, acc[n], 0,0,0);
      }
    }
  }
  __syncthreads();
  float fcv[8];
  #pragma unroll
  for (int n = 0; n < 8; ++n) fcv[n] = fcw[wbase + n*16 + ar];
  {
    const _Float16* Lw = Lsh + (wv*16 + ar)*8;
    #pragma unroll 1
    for (int e = 0; e < E_; ++e) {
      f16x8 lh = *(const f16x8*)(Lw + e*(NW*128));
      float lv[8];
      #pragma unroll
      for (int n = 0; n < 8; ++n) lv[n] = (float)lh[n];
      float s8[4] = {};
      #pragma unroll
      for (int n = 0; n < 8; ++n)
        #pragma unroll
        for (int i = 0; i < 4; ++i) {
          float t = __builtin_amdgcn_exp2f(acc[n][i] + lv[n]);
          s8[i] += fcv[n] * __builtin_amdgcn_rcpf(t + 1.0f);
        }
      #pragma unroll
      for (int off = 1; off < 16; off <<= 1)
        #pragma unroll
        for (int i = 0; i < 4; ++i)
          s8[i] += __shfl_xor(s8[i], off, 64);
      if (ar == 0) {
        #pragma unroll
        for (int i = 0; i < 4; ++i)
          Sp[(wv*BM + kg*4 + i)*20 + e] = s8[i];
      }
    }
  }
  __syncthreads();
  if (tid % 24 == 0) {
    int row = tid / 24;
    float sc2[E_];
    float mx = -1e30f;
    #pragma unroll
    for (int e = 0; e < E_; ++e) {
      float v = 0.f;
      #pragma unroll
      for (int w2 = 0; w2 < NW; ++w2) v += Sp[(w2*BM + row)*20 + e];
      sc2[e] = -2.0f * v;
      mx = fmaxf(mx, sc2[e]);
    }
    float ssum = 0.f;
    #pragma unroll
    for (int e = 0; e < E_; ++e) {
      float p = __builtin_amdgcn_exp2f((sc2[e] - mx) * 1.4426950408889634f);
      sc2[e] = p; ssum += p;
    }
    float rr = __builtin_amdgcn_rcpf(ssum);
    #pragma unroll
    for (int e = 0; e < E_; ++e) Pp[row*20 + e] = sc2[e]*rr;
  }
  __syncthreads();
  {
    const int cg = tid % 96;
    const int rq = tid / 96;
    float o[4][8] = {};
    const f32x4* L4 = (const f32x4*)lab;
    #pragma unroll 1
    for (int e = 0; e < E_; ++e) {
      f32x4 la = L4[e*(H_/4) + cg*2];
      f32x4 lb = L4[e*(H_/4) + cg*2 + 1];
      #pragma unroll
      for (int rr2 = 0; rr2 < 4; ++rr2) {
        float p = Pp[(rq*4 + rr2)*20 + e];
        o[rr2][0] += p*la[0]; o[rr2][1] += p*la[1]; o[rr2][2] += p*la[2]; o[rr2][3] += p*la[3];
        o[rr2][4] += p*lb[0]; o[rr2][5] += p*lb[1]; o[rr2][6] += p*lb[2]; o[rr2][7] += p*lb[3];
      }
    }
    const int cnt = counts[batch];
    #pragma unroll
    for (int rr2 = 0; rr2 < 4; ++rr2) {
      int row = rq*4 + rr2;
      int sp  = s0 + row;
      bool keep = (sp >= T0) && (sp < cnt + T0);
      size_t idx = rowbase + (size_t)row*H_ + cg*8;
      float4 s1 = *(const float4*)(seq + idx);
      float4 s2v = *(const float4*)(seq + idx + 4);
      float4 o1, o2;
      if (keep) { o1 = s1; o2 = s2v; }
      else {
        o1 = make_float4(s1.x + o[rr2][0], s1.y + o[rr2][1], s1.z + o[rr2][2], s1.w + o[rr2][3]);
        o2 = make_float4(s2v.x + o[rr2][4], s2v.y + o[rr2][5], s2v.z + o[rr2][6], s2v.w + o[rr2][7]);
      }
      *(float4*)(out + idx)     = o1;
      *(float4*)(out + idx + 4) = o2;
    }
  }
}

extern "C" void kernel_launch(void* const* d_in, const int* in_sizes, int n_in,
                              void* d_out, int out_size, void* d_ws, size_t ws_size,
                              hipStream_t stream) {
  const float* seq    = (const float*)d_in[0];
  const float* lab    = (const float*)d_in[1];
  const float* attw   = (const float*)d_in[2];
  const float* attb   = (const float*)d_in[3];
  const float* fcw    = (const float*)d_in[4];
  const int*   counts = (const int*)d_in[5];
  float* out = (float*)d_out;

  if (ws_size >= (size_t)WS_NEED) {
    bf16_t* wbf = (bf16_t*)((char*)d_ws + WS_W_OFF);
    f16_t*  pls = (f16_t*)((char*)d_ws + WS_PL_OFF);
    f16_t*  fcg = (f16_t*)((char*)d_ws + WS_FC_OFF);
    f16_t*  pxp = (f16_t*)((char*)d_ws + WS_PX_OFF);
    bf16_t* abf = (ws_size >= (size_t)WS_NEED2)
                ? (bf16_t*)((char*)d_ws + WS_AB_OFF)
                : (bf16_t*)d_out;
    prep_kernel<<<dim3((ROWS*H_/8 + 255)/256), dim3(256), 0, stream>>>(
        attw, lab, attb, fcw, seq, wbf, pls, fcg, abf);
    gemm_xs2<<<dim3((ROWS/G_BM)*(H_/G_BN)), dim3(G_NT), 0, stream>>>(
        abf, wbf, pxp);
    score_ctx<<<dim3(ROWS/K2_R), dim3(256), 0, stream>>>(
        pxp, pls, fcw, seq, lab, counts, out);
  } else {
    ner_fused<<<dim3(ROWS/BM), dim3(NT), 0, stream>>>(seq, lab, attw, attb, fcw, counts, out);
  }
}

// Round 19
// 55.624 us; speedup vs baseline: 1.1583x; 1.0445x over previous
//
#include <hip/hip_runtime.h>
#include <hip/hip_fp16.h>

typedef __bf16 bf16_t;
typedef __bf16 bf16x8 __attribute__((ext_vector_type(8)));
typedef _Float16 f16_t;
typedef _Float16 f16x8 __attribute__((ext_vector_type(8)));
typedef float  f32x4  __attribute__((ext_vector_type(4)));

#define B_ 16
#define S_ 512
#define H_ 768
#define E_ 19
#define T0 3
#define ROWS (B_*S_)
#define SCAL 2.8853900817779268f   // 2*log2(e)
#define ECLAMP_LO (-13.5f)
#define ECLAMP_HI (15.5f)

// ---- workspace layout (bytes) ----
#define WS_W_OFF  0
#define WS_W_SZ   (H_*H_*2)                 // W bf16 prescaled by SCAL
#define WS_PL_OFF (WS_W_OFF + WS_W_SZ)
#define WS_PL_SZ  (E_*H_*2)                 // pl f16 = exp2(SCAL*(L+b)) clamped
#define WS_FC_OFF (WS_PL_OFF + WS_PL_SZ)
#define WS_FC_SZ  (H_*2)                    // fc f16 (layout keep)
#define WS_PX_OFF (WS_FC_OFF + WS_FC_SZ)
#define WS_PX_SZ  (ROWS*H_*2)               // px f16 = exp2(SCAL*x) clamped
#define WS_NEED   (WS_PX_OFF + WS_PX_SZ)
#define WS_AB_OFF WS_NEED
#define WS_AB_SZ  (ROWS*H_*2)               // seq as bf16
#define WS_NEED2  (WS_AB_OFF + WS_AB_SZ)

__device__ __forceinline__ float clamp_e(float v) {
  return fminf(fmaxf(v, ECLAMP_LO), ECLAMP_HI);
}

// ================= prep: W -> bf16*SCAL ; pl table ; fc f16 ; seq -> bf16 ====
__global__ __launch_bounds__(256) void prep_kernel(
    const float* __restrict__ w, const float* __restrict__ lab,
    const float* __restrict__ attb, const float* __restrict__ fcw,
    const float* __restrict__ seq,
    bf16_t* __restrict__ wbf, f16_t* __restrict__ pls,
    f16_t* __restrict__ fcg, bf16_t* __restrict__ abf) {
  int t = blockIdx.x*256 + threadIdx.x;
  int i = t*8;
  if (i < H_*H_) {
    float4 u = *(const float4*)(w + i);
    float4 v = *(const float4*)(w + i + 4);
    bf16x8 b;
    b[0]=(bf16_t)(u.x*SCAL); b[1]=(bf16_t)(u.y*SCAL); b[2]=(bf16_t)(u.z*SCAL); b[3]=(bf16_t)(u.w*SCAL);
    b[4]=(bf16_t)(v.x*SCAL); b[5]=(bf16_t)(v.y*SCAL); b[6]=(bf16_t)(v.z*SCAL); b[7]=(bf16_t)(v.w*SCAL);
    *(bf16x8*)(wbf + i) = b;
  }
  if (t < E_*H_) {
    int col = t % H_;
    float e2 = clamp_e((lab[t] + attb[col]) * SCAL);
    pls[t] = (f16_t)__builtin_amdgcn_exp2f(e2);
  }
  if (t < H_) fcg[t] = (f16_t)fcw[t];
  if (i < ROWS*H_) {
    float4 u = *(const float4*)(seq + i);
    float4 v = *(const float4*)(seq + i + 4);
    bf16x8 b;
    b[0]=(bf16_t)u.x; b[1]=(bf16_t)u.y; b[2]=(bf16_t)u.z; b[3]=(bf16_t)u.w;
    b[4]=(bf16_t)v.x; b[5]=(bf16_t)v.y; b[6]=(bf16_t)v.z; b[7]=(bf16_t)v.w;
    *(bf16x8*)(abf + i) = b;
  }
}

// ================= K1: m97-style 128x128x64 GEMM -> px f16 (proven) =========
#define G_BM 128
#define G_BN 128
#define G_BK 64
#define G_NT 256
#define G_STEPS (H_/G_BK)   // 12

__global__ __launch_bounds__(G_NT, 2) void gemm_xs2(
    const bf16_t* __restrict__ abf,
    const bf16_t* __restrict__ wbf, f16_t* __restrict__ px) {
  __shared__ __align__(16) unsigned char smem[32768];   // A [0,16K) B [16K,32K)
  const int tid  = threadIdx.x;
  const int lane = tid & 63, wv = tid >> 6;
  const int bid  = blockIdx.x;
  const int wg   = (bid & 7)*48 + (bid >> 3);   // bijective, 384%8==0
  const int rt   = wg / 6, ct = wg % 6;
  const int arow0 = rt * G_BM;
  const int bcol0 = ct * G_BN;
  const int wr = wv >> 1, wc = wv & 1;
  const int ar = lane & 15, kg = lane >> 4;

  f32x4 acc[4][4] = {};

  auto stage = [&](int s) {
    const int k0 = s * G_BK;
    #pragma unroll
    for (int it = 0; it < 4; ++it) {
      int Lb  = (wv*4 + it) * 1024;        // wave-uniform LDS base
      int L   = Lb + lane*16;              // this lane's linear slot
      int row = L >> 7;                    // /128 (tile row)
      int c   = (L >> 4) & 7;              // 16B chunk within row
      int cs  = c ^ (row & 7);             // inverse swizzle on source
      const bf16_t* srcA = abf + (size_t)(arow0 + row)*H_ + k0 + cs*8;
      __builtin_amdgcn_global_load_lds(
          (const __attribute__((address_space(1))) void*)srcA,
          (__attribute__((address_space(3))) void*)(smem + Lb), 16, 0, 0);
      const bf16_t* srcB = wbf + (size_t)(bcol0 + row)*H_ + k0 + cs*8;
      __builtin_amdgcn_global_load_lds(
          (const __attribute__((address_space(1))) void*)srcB,
          (__attribute__((address_space(3))) void*)(smem + 16384 + Lb), 16, 0, 0);
    }
  };

  stage(0);
  #pragma unroll 1
  for (int s = 0; s < G_STEPS; ++s) {
    __syncthreads();                       // staging visible (vmcnt drained)
    #pragma unroll
    for (int ks = 0; ks < 2; ++ks) {
      bf16x8 af[4], bfr[4];
      #pragma unroll
      for (int mf = 0; mf < 4; ++mf) {
        int row = wr*64 + mf*16 + ar;
        int g2  = ks*4 + kg;
        af[mf] = *(const bf16x8*)(smem + row*128 + ((g2 ^ (row & 7)) << 4));
      }
      #pragma unroll
      for (int nf = 0; nf < 4; ++nf) {
        int row = wc*64 + nf*16 + ar;
        int g2  = ks*4 + kg;
        bfr[nf] = *(const bf16x8*)(smem + 16384 + row*128 + ((g2 ^ (row & 7)) << 4));
      }
      #pragma unroll
      for (int mf = 0; mf < 4; ++mf)
        #pragma unroll
        for (int nf = 0; nf < 4; ++nf)
          acc[mf][nf] = __builtin_amdgcn_mfma_f32_16x16x32_bf16(af[mf], bfr[nf], acc[mf][nf], 0,0,0);
    }
    __syncthreads();                       // all waves done reading
    if (s + 1 < G_STEPS) stage(s + 1);
  }

  // epilogue: px[row][col] = f16(exp2(clamp(acc)))   (acc = SCAL * x_attn_nob)
  #pragma unroll
  for (int mf = 0; mf < 4; ++mf) {
    int rbase = arow0 + wr*64 + mf*16 + kg*4;
    #pragma unroll
    for (int nf = 0; nf < 4; ++nf) {
      int col = bcol0 + wc*64 + nf*16 + ar;
      #pragma unroll
      for (int i = 0; i < 4; ++i) {
        float v = clamp_e(acc[mf][nf][i]);
        px[(size_t)(rbase + i)*H_ + col] = (f16_t)__builtin_amdgcn_exp2f(v);
      }
    }
  }
}

// ================= K2: score + softmax + ctx (fma_mix eval, unroll-2 c-loop,
//                   block-uniform keep-all early exit) =======================
// 2048 blocks x 256 thr; 4 rows/block; group(g=tid/16): r=g&3, eq=g>>2
#define K2_R   4
#define K2_PAD 1552                      // LDS row stride (bank-spread)
#define K2_SALL (K2_R*K2_PAD)            // 6208
#define K2_PP   (K2_SALL + K2_R*20*4)    // 6528
#define K2_LDS  (K2_PP + K2_R*20*4)      // 6848
__global__ __launch_bounds__(256, 6) void score_ctx(
    const f16_t* __restrict__ px, const f16_t* __restrict__ pls,
    const float* __restrict__ fcw, const float* __restrict__ seq,
    const float* __restrict__ lab, const int* __restrict__ counts,
    float* __restrict__ out) {
  __shared__ __align__(16) unsigned char smem[K2_LDS];
  float* Sall = (float*)(smem + K2_SALL);
  float* Pp   = (float*)(smem + K2_PP);
  const int tid = threadIdx.x;
  const int r0  = blockIdx.x * K2_R;     // global row base

  // ---- keep-all early exit: rows [T0, cnt+T0) are exact passthrough.
  //      Block-uniform condition (r0, counts[batch]) -> no divergence.
  const int batch = r0 >> 9;
  const int cnt   = counts[batch];
  const int sp0   = r0 & 511;
  if (sp0 >= T0 && sp0 + (K2_R - 1) < cnt + T0) {
    #pragma unroll 1
    for (int i = tid; i < K2_R*(H_/4); i += 256) {   // 768 f32x4 chunks
      int row = r0 + i/(H_/4), c4 = i%(H_/4);
      size_t idx = (size_t)row*H_ + (size_t)c4*4;
      *(f32x4*)(out + idx) = *(const f32x4*)(seq + idx);
    }
    return;
  }

  // stage px rows (f16), padded stride
  for (int i = tid; i < K2_R*(H_/8); i += 256) {   // 384 chunks
    int row = i / 96, kv = i % 96;
    f16x8 v = *(const f16x8*)(px + (size_t)(r0 + row)*H_ + kv*8);
    *(f16x8*)(smem + row*K2_PAD + kv*16) = v;
  }
  __syncthreads();

  const int g = tid >> 4, k = tid & 15;
  const int r = g & 3, eq = g >> 2;
  const f16_t* xrow = (const f16_t*)(smem + r*K2_PAD + k*96);
  const int ebase = eq*5;
  const f16_t* lbase = pls + ebase*H_ + k*48;

  float s[5] = {};
  #pragma unroll 2
  for (int c = 0; c < 6; ++c) {
    f16x8 xh = *(const f16x8*)(xrow + c*8);             // px (LDS)
    f32x4 f0 = *(const f32x4*)(fcw + k*48 + c*8);       // fc f32 (L1/L2)
    f32x4 f1 = *(const f32x4*)(fcw + k*48 + c*8 + 4);
    #pragma unroll
    for (int j = 0; j < 5; ++j) {
      if (j == 4 && eq == 3) continue;       // e=19 doesn't exist (wave-uniform)
      f16x8 lh = *(const f16x8*)(lbase + j*H_ + c*8);   // pl (L1/L2)
      #pragma unroll
      for (int q = 0; q < 8; ++q) {
        float u  = (float)xh[q] * (float)lh[q] + 1.0f;  // v_fma_mix_f32
        float rr = __builtin_amdgcn_rcpf(u);            // v_rcp_f32
        float fq = (q < 4) ? f0[q] : f1[q-4];
        s[j] += fq * rr;                                // v_fmac_f32
      }
    }
  }
  #pragma unroll
  for (int off = 1; off < 16; off <<= 1)
    #pragma unroll
    for (int j = 0; j < 5; ++j)
      s[j] += __shfl_xor(s[j], off, 64);
  if (k == 0) {
    #pragma unroll
    for (int j = 0; j < 5; ++j) {
      int e = ebase + j;
      if (e < E_) Sall[r*20 + e] = s[j];
    }
  }
  __syncthreads();

  // softmax per row (logits = -2*S, const shift drops out)
  if (tid < K2_R) {
    float s2[E_]; float mx = -1e30f;
    #pragma unroll
    for (int e = 0; e < E_; ++e) {
      float v = -2.0f * Sall[tid*20 + e];
      s2[e] = v; mx = fmaxf(mx, v);
    }
    float ssum = 0.f;
    #pragma unroll
    for (int e = 0; e < E_; ++e) {
      float pr = __builtin_amdgcn_exp2f((s2[e] - mx) * 1.4426950408889634f);
      s2[e] = pr; ssum += pr;
    }
    float rr = __builtin_amdgcn_rcpf(ssum);
    #pragma unroll
    for (int e = 0; e < E_; ++e) Pp[tid*20 + e] = s2[e]*rr;
  }
  __syncthreads();

  // ctx + residual + keep-mask; 192 threads own one float4-col each, 4 rows
  if (tid < 192) {
    f32x4 o4[K2_R] = {};
    #pragma unroll 1
    for (int e = 0; e < E_; ++e) {
      f32x4 la = *(const f32x4*)(lab + e*H_ + tid*4);
      #pragma unroll
      for (int rr2 = 0; rr2 < K2_R; ++rr2) {
        float pv = Pp[rr2*20 + e];
        o4[rr2] += pv * la;
      }
    }
    #pragma unroll
    for (int rr2 = 0; rr2 < K2_R; ++rr2) {
      int row = r0 + rr2;
      int sp  = row & 511;
      bool keep = (sp >= T0) && (sp < cnt + T0);
      size_t idx = (size_t)row*H_ + tid*4;
      f32x4 sv = *(const f32x4*)(seq + idx);
      f32x4 ov = keep ? sv : (sv + o4[rr2]);
      *(f32x4*)(out + idx) = ov;
    }
  }
}

// ================= fallback: round-3 fused kernel (passed) =================
#define BM 16
#define NW 6
#define NT (NW*64)
#define A_SZ   (BM*H_*2)
#define LS_OFF A_SZ
#define LS_SZ  (E_*H_*2)
#define LDS_SZ (A_SZ + LS_SZ)
#define SP_OFF 0
#define PP_OFF (NW*BM*20*4)

__global__ __launch_bounds__(NT, 3) void ner_fused(
    const float* __restrict__ seq, const float* __restrict__ lab,
    const float* __restrict__ attw, const float* __restrict__ attb,
    const float* __restrict__ fcw, const int* __restrict__ counts,
    float* __restrict__ out)
{
  __shared__ __align__(16) unsigned char smem[LDS_SZ];
  _Float16* Lsh = (_Float16*)(smem + LS_OFF);
  float* Sp = (float*)(smem + SP_OFF);
  float* Pp = (float*)(smem + PP_OFF);
  const int tid   = threadIdx.x;
  const int blk   = blockIdx.x;
  const int batch = blk >> 5;
  const int s0    = (blk & 31) * BM;
  const size_t rowbase = ((size_t)batch * S_ + s0) * H_;
  {
    const float4* src = (const float4*)(seq + rowbase);
    #pragma unroll
    for (int i = 0; i < (BM*H_/8)/NT; ++i) {
      int idx = i*NT + tid;
      int row = idx / (H_/8);
      int kv  = idx % (H_/8);
      float4 u = src[row*(H_/4) + kv*2];
      float4 v = src[row*(H_/4) + kv*2 + 1];
      bf16x8 b;
      b[0]=(bf16_t)u.x; b[1]=(bf16_t)u.y; b[2]=(bf16_t)u.z; b[3]=(bf16_t)u.w;
      b[4]=(bf16_t)v.x; b[5]=(bf16_t)v.y; b[6]=(bf16_t)v.z; b[7]=(bf16_t)v.w;
      int byte = row*(H_*2) + kv*16;
      *(bf16x8*)(smem + (byte ^ ((row & 7) << 4))) = b;
    }
  }
  for (int i = tid*4; i < E_*H_; i += NT*4) {
    int c = i % H_;
    float4 l4 = *(const float4*)(lab + i);
    float4 b4 = *(const float4*)(attb + c);
    int e = i / H_;
    #pragma unroll
    for (int j = 0; j < 4; ++j) {
      int col = c + j;
      int wv2 = col >> 7, rr = col & 127, n = rr >> 4, arr = rr & 15;
      float v = ((&l4.x)[j] + (&b4.x)[j]) * SCAL;
      Lsh[((e*NW + wv2)*16 + arr)*8 + n] = (_Float16)v;
    }
  }
  __syncthreads();
  const int lane = tid & 63;
  const int wv   = tid >> 6;
  const int ar   = lane & 15;
  const int kg   = lane >> 4;
  const int wbase = wv * (H_/NW);
  f32x4 acc[8] = {};
  {
    const int a_sw = (ar & 7) << 4;
    #pragma unroll 1
    for (int step = 0; step < H_/32; ++step) {
      int kb = step*64 + kg*16;
      bf16x8 a0 = *(const bf16x8*)(smem + ((ar*1536 + kb) ^ a_sw));
      int k = step*32 + kg*8;
      #pragma unroll
      for (int n = 0; n < 8; ++n) {
        int gcol = wbase + n*16 + ar;
        float4 u = *(const float4*)(attw + (size_t)gcol*H_ + k);
        float4 v = *(const float4*)(attw + (size_t)gcol*H_ + k + 4);
        bf16x8 bb;
        bb[0]=(bf16_t)(u.x*SCAL); bb[1]=(bf16_t)(u.y*SCAL); bb[2]=(bf16_t)(u.z*SCAL); bb[3]=(bf16_t)(u.w*SCAL);
        bb[4]=(bf16_t)(v.x*SCAL); bb[5]=(bf16_t)(v.y*SCAL); bb[6]=(bf16_t)(v.z*SCAL); bb[7]=(bf16_t)(v.w*SCAL);
        acc[n] = __builtin_amdgcn_mfma_f32_16x16x32_bf16(a0, bb, acc[n], 0,0,0);
      }
    }
  }
  __syncthreads();
  float fcv[8];
  #pragma unroll
  for (int n = 0; n < 8; ++n) fcv[n] = fcw[wbase + n*16 + ar];
  {
    const _Float16* Lw = Lsh + (wv*16 + ar)*8;
    #pragma unroll 1
    for (int e = 0; e < E_; ++e) {
      f16x8 lh = *(const f16x8*)(Lw + e*(NW*128));
      float lv[8];
      #pragma unroll
      for (int n = 0; n < 8; ++n) lv[n] = (float)lh[n];
      float s8[4] = {};
      #pragma unroll
      for (int n = 0; n < 8; ++n)
        #pragma unroll
        for (int i = 0; i < 4; ++i) {
          float t = __builtin_amdgcn_exp2f(acc[n][i] + lv[n]);
          s8[i] += fcv[n] * __builtin_amdgcn_rcpf(t + 1.0f);
        }
      #pragma unroll
      for (int off = 1; off < 16; off <<= 1)
        #pragma unroll
        for (int i = 0; i < 4; ++i)
          s8[i] += __shfl_xor(s8[i], off, 64);
      if (ar == 0) {
        #pragma unroll
        for (int i = 0; i < 4; ++i)
          Sp[(wv*BM + kg*4 + i)*20 + e] = s8[i];
      }
    }
  }
  __syncthreads();
  if (tid % 24 == 0) {
    int row = tid / 24;
    float sc2[E_];
    float mx = -1e30f;
    #pragma unroll
    for (int e = 0; e < E_; ++e) {
      float v = 0.f;
      #pragma unroll
      for (int w2 = 0; w2 < NW; ++w2) v += Sp[(w2*BM + row)*20 + e];
      sc2[e] = -2.0f * v;
      mx = fmaxf(mx, sc2[e]);
    }
    float ssum = 0.f;
    #pragma unroll
    for (int e = 0; e < E_; ++e) {
      float p = __builtin_amdgcn_exp2f((sc2[e] - mx) * 1.4426950408889634f);
      sc2[e] = p; ssum += p;
    }
    float rr = __builtin_amdgcn_rcpf(ssum);
    #pragma unroll
    for (int e = 0; e < E_; ++e) Pp[row*20 + e] = sc2[e]*rr;
  }
  __syncthreads();
  {
    const int cg = tid % 96;
    const int rq = tid / 96;
    float o[4][8] = {};
    const f32x4* L4 = (const f32x4*)lab;
    #pragma unroll 1
    for (int e = 0; e < E_; ++e) {
      f32x4 la = L4[e*(H_/4) + cg*2];
      f32x4 lb = L4[e*(H_/4) + cg*2 + 1];
      #pragma unroll
      for (int rr2 = 0; rr2 < 4; ++rr2) {
        float p = Pp[(rq*4 + rr2)*20 + e];
        o[rr2][0] += p*la[0]; o[rr2][1] += p*la[1]; o[rr2][2] += p*la[2]; o[rr2][3] += p*la[3];
        o[rr2][4] += p*lb[0]; o[rr2][5] += p*lb[1]; o[rr2][6] += p*lb[2]; o[rr2][7] += p*lb[3];
      }
    }
    const int cnt = counts[batch];
    #pragma unroll
    for (int rr2 = 0; rr2 < 4; ++rr2) {
      int row = rq*4 + rr2;
      int sp  = s0 + row;
      bool keep = (sp >= T0) && (sp < cnt + T0);
      size_t idx = rowbase + (size_t)row*H_ + cg*8;
      float4 s1 = *(const float4*)(seq + idx);
      float4 s2v = *(const float4*)(seq + idx + 4);
      float4 o1, o2;
      if (keep) { o1 = s1; o2 = s2v; }
      else {
        o1 = make_float4(s1.x + o[rr2][0], s1.y + o[rr2][1], s1.z + o[rr2][2], s1.w + o[rr2][3]);
        o2 = make_float4(s2v.x + o[rr2][4], s2v.y + o[rr2][5], s2v.z + o[rr2][6], s2v.w + o[rr2][7]);
      }
      *(float4*)(out + idx)     = o1;
      *(float4*)(out + idx + 4) = o2;
    }
  }
}

extern "C" void kernel_launch(void* const* d_in, const int* in_sizes, int n_in,
                              void* d_out, int out_size, void* d_ws, size_t ws_size,
                              hipStream_t stream) {
  const float* seq    = (const float*)d_in[0];
  const float* lab    = (const float*)d_in[1];
  const float* attw   = (const float*)d_in[2];
  const float* attb   = (const float*)d_in[3];
  const float* fcw    = (const float*)d_in[4];
  const int*   counts = (const int*)d_in[5];
  float* out = (float*)d_out;

  if (ws_size >= (size_t)WS_NEED) {
    bf16_t* wbf = (bf16_t*)((char*)d_ws + WS_W_OFF);
    f16_t*  pls = (f16_t*)((char*)d_ws + WS_PL_OFF);
    f16_t*  fcg = (f16_t*)((char*)d_ws + WS_FC_OFF);
    f16_t*  pxp = (f16_t*)((char*)d_ws + WS_PX_OFF);
    bf16_t* abf = (ws_size >= (size_t)WS_NEED2)
                ? (bf16_t*)((char*)d_ws + WS_AB_OFF)
                : (bf16_t*)d_out;
    prep_kernel<<<dim3((ROWS*H_/8 + 255)/256), dim3(256), 0, stream>>>(
        attw, lab, attb, fcw, seq, wbf, pls, fcg, abf);
    gemm_xs2<<<dim3((ROWS/G_BM)*(H_/G_BN)), dim3(G_NT), 0, stream>>>(
        abf, wbf, pxp);
    score_ctx<<<dim3(ROWS/K2_R), dim3(256), 0, stream>>>(
        pxp, pls, fcw, seq, lab, counts, out);
  } else {
    ner_fused<<<dim3(ROWS/BM), dim3(NT), 0, stream>>>(seq, lab, attw, attb, fcw, counts, out);
  }
}

// Round 20
// 55.453 us; speedup vs baseline: 1.1619x; 1.0031x over previous
//
#include <hip/hip_runtime.h>
#include <hip/hip_fp16.h>

typedef __bf16 bf16_t;
typedef __bf16 bf16x8 __attribute__((ext_vector_type(8)));
typedef _Float16 f16_t;
typedef _Float16 f16x8 __attribute__((ext_vector_type(8)));
typedef float  f32x4  __attribute__((ext_vector_type(4)));

#define B_ 16
#define S_ 512
#define H_ 768
#define E_ 19
#define T0 3
#define ROWS (B_*S_)
#define SCAL 2.8853900817779268f   // 2*log2(e)
#define ECLAMP_LO (-13.5f)
#define ECLAMP_HI (15.5f)

// ---- workspace layout (bytes) ----
#define WS_W_OFF  0
#define WS_W_SZ   (H_*H_*2)                 // W bf16 prescaled by SCAL
#define WS_PL_OFF (WS_W_OFF + WS_W_SZ)
#define WS_PL_SZ  (E_*H_*2)                 // pl f16 = exp2(SCAL*(L+b)) clamped
#define WS_FC_OFF (WS_PL_OFF + WS_PL_SZ)
#define WS_FC_SZ  (H_*2)                    // fc f16 (layout keep)
#define WS_PX_OFF (WS_FC_OFF + WS_FC_SZ)
#define WS_PX_SZ  (ROWS*H_*2)               // px f16 = exp2(SCAL*x) clamped
#define WS_NEED   (WS_PX_OFF + WS_PX_SZ)
#define WS_AB_OFF WS_NEED
#define WS_AB_SZ  (ROWS*H_*2)               // seq as bf16
#define WS_NEED2  (WS_AB_OFF + WS_AB_SZ)

__device__ __forceinline__ float clamp_e(float v) {
  return fminf(fmaxf(v, ECLAMP_LO), ECLAMP_HI);
}
// 128-row GEMM tile fully inside the keep range [T0, cnt+T0)?
__device__ __forceinline__ bool tile_keep(int spt, int cnt) {
  return (spt >= T0) && (spt + 128 <= cnt + T0);
}

// ================= prep: W -> bf16*SCAL ; pl table ; fc f16 ; seq -> bf16 ====
__global__ __launch_bounds__(256) void prep_kernel(
    const float* __restrict__ w, const float* __restrict__ lab,
    const float* __restrict__ attb, const float* __restrict__ fcw,
    const float* __restrict__ seq, const int* __restrict__ counts,
    bf16_t* __restrict__ wbf, f16_t* __restrict__ pls,
    f16_t* __restrict__ fcg, bf16_t* __restrict__ abf) {
  int t = blockIdx.x*256 + threadIdx.x;
  int i = t*8;
  if (i < H_*H_) {
    float4 u = *(const float4*)(w + i);
    float4 v = *(const float4*)(w + i + 4);
    bf16x8 b;
    b[0]=(bf16_t)(u.x*SCAL); b[1]=(bf16_t)(u.y*SCAL); b[2]=(bf16_t)(u.z*SCAL); b[3]=(bf16_t)(u.w*SCAL);
    b[4]=(bf16_t)(v.x*SCAL); b[5]=(bf16_t)(v.y*SCAL); b[6]=(bf16_t)(v.z*SCAL); b[7]=(bf16_t)(v.w*SCAL);
    *(bf16x8*)(wbf + i) = b;
  }
  if (t < E_*H_) {
    int col = t % H_;
    float e2 = clamp_e((lab[t] + attb[col]) * SCAL);
    pls[t] = (f16_t)__builtin_amdgcn_exp2f(e2);
  }
  if (t < H_) fcg[t] = (f16_t)fcw[t];
  if (i < ROWS*H_) {
    int row = i / H_;
    int spt = (row & 511) & ~127;           // tile start within batch
    if (!tile_keep(spt, counts[row >> 9])) {  // skip rows of skippable tiles
      float4 u = *(const float4*)(seq + i);
      float4 v = *(const float4*)(seq + i + 4);
      bf16x8 b;
      b[0]=(bf16_t)u.x; b[1]=(bf16_t)u.y; b[2]=(bf16_t)u.z; b[3]=(bf16_t)u.w;
      b[4]=(bf16_t)v.x; b[5]=(bf16_t)v.y; b[6]=(bf16_t)v.z; b[7]=(bf16_t)v.w;
      *(bf16x8*)(abf + i) = b;
    }
  }
}

// ================= K1: m97-style 128x128x64 GEMM -> px f16 (proven) =========
// + block-uniform tile skip: fully-keep tiles' px is never read by K2.
#define G_BM 128
#define G_BN 128
#define G_BK 64
#define G_NT 256
#define G_STEPS (H_/G_BK)   // 12

__global__ __launch_bounds__(G_NT, 2) void gemm_xs2(
    const bf16_t* __restrict__ abf, const int* __restrict__ counts,
    const bf16_t* __restrict__ wbf, f16_t* __restrict__ px) {
  __shared__ __align__(16) unsigned char smem[32768];   // A [0,16K) B [16K,32K)
  const int tid  = threadIdx.x;
  const int lane = tid & 63, wv = tid >> 6;
  const int bid  = blockIdx.x;
  const int wg   = (bid & 7)*48 + (bid >> 3);   // bijective, 384%8==0
  const int rt   = wg / 6, ct = wg % 6;
  const int arow0 = rt * G_BM;
  const int bcol0 = ct * G_BN;

  // ---- tile skip (block-uniform): px of fully-keep tiles is never read ----
  const int batch = arow0 >> 9;
  const int cnt   = counts[batch];
  if (tile_keep(arow0 & 511, cnt)) return;

  const int wr = wv >> 1, wc = wv & 1;
  const int ar = lane & 15, kg = lane >> 4;

  f32x4 acc[4][4] = {};

  auto stage = [&](int s) {
    const int k0 = s * G_BK;
    #pragma unroll
    for (int it = 0; it < 4; ++it) {
      int Lb  = (wv*4 + it) * 1024;        // wave-uniform LDS base
      int L   = Lb + lane*16;              // this lane's linear slot
      int row = L >> 7;                    // /128 (tile row)
      int c   = (L >> 4) & 7;              // 16B chunk within row
      int cs  = c ^ (row & 7);             // inverse swizzle on source
      const bf16_t* srcA = abf + (size_t)(arow0 + row)*H_ + k0 + cs*8;
      __builtin_amdgcn_global_load_lds(
          (const __attribute__((address_space(1))) void*)srcA,
          (__attribute__((address_space(3))) void*)(smem + Lb), 16, 0, 0);
      const bf16_t* srcB = wbf + (size_t)(bcol0 + row)*H_ + k0 + cs*8;
      __builtin_amdgcn_global_load_lds(
          (const __attribute__((address_space(1))) void*)srcB,
          (__attribute__((address_space(3))) void*)(smem + 16384 + Lb), 16, 0, 0);
    }
  };

  stage(0);
  #pragma unroll 1
  for (int s = 0; s < G_STEPS; ++s) {
    __syncthreads();                       // staging visible (vmcnt drained)
    #pragma unroll
    for (int ks = 0; ks < 2; ++ks) {
      bf16x8 af[4], bfr[4];
      #pragma unroll
      for (int mf = 0; mf < 4; ++mf) {
        int row = wr*64 + mf*16 + ar;
        int g2  = ks*4 + kg;
        af[mf] = *(const bf16x8*)(smem + row*128 + ((g2 ^ (row & 7)) << 4));
      }
      #pragma unroll
      for (int nf = 0; nf < 4; ++nf) {
        int row = wc*64 + nf*16 + ar;
        int g2  = ks*4 + kg;
        bfr[nf] = *(const bf16x8*)(smem + 16384 + row*128 + ((g2 ^ (row & 7)) << 4));
      }
      #pragma unroll
      for (int mf = 0; mf < 4; ++mf)
        #pragma unroll
        for (int nf = 0; nf < 4; ++nf)
          acc[mf][nf] = __builtin_amdgcn_mfma_f32_16x16x32_bf16(af[mf], bfr[nf], acc[mf][nf], 0,0,0);
    }
    __syncthreads();                       // all waves done reading
    if (s + 1 < G_STEPS) stage(s + 1);
  }

  // epilogue: px[row][col] = f16(exp2(clamp(acc))); skip rows whose 4-row
  // K2 block is fully-keep (their px is never read).
  #pragma unroll
  for (int mf = 0; mf < 4; ++mf) {
    int rbase = arow0 + wr*64 + mf*16 + kg*4;
    int sp4   = rbase & 511;               // 4-aligned block start in batch
    bool k4   = (sp4 >= T0) && (sp4 + 4 <= cnt + T0);
    if (k4) continue;
    #pragma unroll
    for (int nf = 0; nf < 4; ++nf) {
      int col = bcol0 + wc*64 + nf*16 + ar;
      #pragma unroll
      for (int i = 0; i < 4; ++i) {
        float v = clamp_e(acc[mf][nf][i]);
        px[(size_t)(rbase + i)*H_ + col] = (f16_t)__builtin_amdgcn_exp2f(v);
      }
    }
  }
}

// ================= K2: score + softmax + ctx (fma_mix eval, unroll-2 c-loop,
//                   block-uniform keep-all early exit) =======================
#define K2_R   4
#define K2_PAD 1552                      // LDS row stride (bank-spread)
#define K2_SALL (K2_R*K2_PAD)            // 6208
#define K2_PP   (K2_SALL + K2_R*20*4)    // 6528
#define K2_LDS  (K2_PP + K2_R*20*4)      // 6848
__global__ __launch_bounds__(256, 6) void score_ctx(
    const f16_t* __restrict__ px, const f16_t* __restrict__ pls,
    const float* __restrict__ fcw, const float* __restrict__ seq,
    const float* __restrict__ lab, const int* __restrict__ counts,
    float* __restrict__ out) {
  __shared__ __align__(16) unsigned char smem[K2_LDS];
  float* Sall = (float*)(smem + K2_SALL);
  float* Pp   = (float*)(smem + K2_PP);
  const int tid = threadIdx.x;
  const int r0  = blockIdx.x * K2_R;     // global row base

  // ---- keep-all early exit (block-uniform) ----
  const int batch = r0 >> 9;
  const int cnt   = counts[batch];
  const int sp0   = r0 & 511;
  if (sp0 >= T0 && sp0 + (K2_R - 1) < cnt + T0) {
    #pragma unroll 1
    for (int i = tid; i < K2_R*(H_/4); i += 256) {   // 768 f32x4 chunks
      int row = r0 + i/(H_/4), c4 = i%(H_/4);
      size_t idx = (size_t)row*H_ + (size_t)c4*4;
      *(f32x4*)(out + idx) = *(const f32x4*)(seq + idx);
    }
    return;
  }

  // stage px rows (f16), padded stride
  for (int i = tid; i < K2_R*(H_/8); i += 256) {   // 384 chunks
    int row = i / 96, kv = i % 96;
    f16x8 v = *(const f16x8*)(px + (size_t)(r0 + row)*H_ + kv*8);
    *(f16x8*)(smem + row*K2_PAD + kv*16) = v;
  }
  __syncthreads();

  const int g = tid >> 4, k = tid & 15;
  const int r = g & 3, eq = g >> 2;
  const f16_t* xrow = (const f16_t*)(smem + r*K2_PAD + k*96);
  const int ebase = eq*5;
  const f16_t* lbase = pls + ebase*H_ + k*48;

  float s[5] = {};
  #pragma unroll 2
  for (int c = 0; c < 6; ++c) {
    f16x8 xh = *(const f16x8*)(xrow + c*8);             // px (LDS)
    f32x4 f0 = *(const f32x4*)(fcw + k*48 + c*8);       // fc f32 (L1/L2)
    f32x4 f1 = *(const f32x4*)(fcw + k*48 + c*8 + 4);
    #pragma unroll
    for (int j = 0; j < 5; ++j) {
      if (j == 4 && eq == 3) continue;       // e=19 doesn't exist (wave-uniform)
      f16x8 lh = *(const f16x8*)(lbase + j*H_ + c*8);   // pl (L1/L2)
      #pragma unroll
      for (int q = 0; q < 8; ++q) {
        float u  = (float)xh[q] * (float)lh[q] + 1.0f;  // v_fma_mix_f32
        float rr = __builtin_amdgcn_rcpf(u);            // v_rcp_f32
        float fq = (q < 4) ? f0[q] : f1[q-4];
        s[j] += fq * rr;                                // v_fmac_f32
      }
    }
  }
  #pragma unroll
  for (int off = 1; off < 16; off <<= 1)
    #pragma unroll
    for (int j = 0; j < 5; ++j)
      s[j] += __shfl_xor(s[j], off, 64);
  if (k == 0) {
    #pragma unroll
    for (int j = 0; j < 5; ++j) {
      int e = ebase + j;
      if (e < E_) Sall[r*20 + e] = s[j];
    }
  }
  __syncthreads();

  // softmax per row (logits = -2*S, const shift drops out)
  if (tid < K2_R) {
    float s2[E_]; float mx = -1e30f;
    #pragma unroll
    for (int e = 0; e < E_; ++e) {
      float v = -2.0f * Sall[tid*20 + e];
      s2[e] = v; mx = fmaxf(mx, v);
    }
    float ssum = 0.f;
    #pragma unroll
    for (int e = 0; e < E_; ++e) {
      float pr = __builtin_amdgcn_exp2f((s2[e] - mx) * 1.4426950408889634f);
      s2[e] = pr; ssum += pr;
    }
    float rr = __builtin_amdgcn_rcpf(ssum);
    #pragma unroll
    for (int e = 0; e < E_; ++e) Pp[tid*20 + e] = s2[e]*rr;
  }
  __syncthreads();

  // ctx + residual + keep-mask; 192 threads own one float4-col each, 4 rows
  if (tid < 192) {
    f32x4 o4[K2_R] = {};
    #pragma unroll 1
    for (int e = 0; e < E_; ++e) {
      f32x4 la = *(const f32x4*)(lab + e*H_ + tid*4);
      #pragma unroll
      for (int rr2 = 0; rr2 < K2_R; ++rr2) {
        float pv = Pp[rr2*20 + e];
        o4[rr2] += pv * la;
      }
    }
    #pragma unroll
    for (int rr2 = 0; rr2 < K2_R; ++rr2) {
      int row = r0 + rr2;
      int sp  = row & 511;
      bool keep = (sp >= T0) && (sp < cnt + T0);
      size_t idx = (size_t)row*H_ + tid*4;
      f32x4 sv = *(const f32x4*)(seq + idx);
      f32x4 ov = keep ? sv : (sv + o4[rr2]);
      *(f32x4*)(out + idx) = ov;
    }
  }
}

// ================= fallback: round-3 fused kernel (passed) =================
#define BM 16
#define NW 6
#define NT (NW*64)
#define A_SZ   (BM*H_*2)
#define LS_OFF A_SZ
#define LS_SZ  (E_*H_*2)
#define LDS_SZ (A_SZ + LS_SZ)
#define SP_OFF 0
#define PP_OFF (NW*BM*20*4)

__global__ __launch_bounds__(NT, 3) void ner_fused(
    const float* __restrict__ seq, const float* __restrict__ lab,
    const float* __restrict__ attw, const float* __restrict__ attb,
    const float* __restrict__ fcw, const int* __restrict__ counts,
    float* __restrict__ out)
{
  __shared__ __align__(16) unsigned char smem[LDS_SZ];
  _Float16* Lsh = (_Float16*)(smem + LS_OFF);
  float* Sp = (float*)(smem + SP_OFF);
  float* Pp = (float*)(smem + PP_OFF);
  const int tid   = threadIdx.x;
  const int blk   = blockIdx.x;
  const int batch = blk >> 5;
  const int s0    = (blk & 31) * BM;
  const size_t rowbase = ((size_t)batch * S_ + s0) * H_;
  {
    const float4* src = (const float4*)(seq + rowbase);
    #pragma unroll
    for (int i = 0; i < (BM*H_/8)/NT; ++i) {
      int idx = i*NT + tid;
      int row = idx / (H_/8);
      int kv  = idx % (H_/8);
      float4 u = src[row*(H_/4) + kv*2];
      float4 v = src[row*(H_/4) + kv*2 + 1];
      bf16x8 b;
      b[0]=(bf16_t)u.x; b[1]=(bf16_t)u.y; b[2]=(bf16_t)u.z; b[3]=(bf16_t)u.w;
      b[4]=(bf16_t)v.x; b[5]=(bf16_t)v.y; b[6]=(bf16_t)v.z; b[7]=(bf16_t)v.w;
      int byte = row*(H_*2) + kv*16;
      *(bf16x8*)(smem + (byte ^ ((row & 7) << 4))) = b;
    }
  }
  for (int i = tid*4; i < E_*H_; i += NT*4) {
    int c = i % H_;
    float4 l4 = *(const float4*)(lab + i);
    float4 b4 = *(const float4*)(attb + c);
    int e = i / H_;
    #pragma unroll
    for (int j = 0; j < 4; ++j) {
      int col = c + j;
      int wv2 = col >> 7, rr = col & 127, n = rr >> 4, arr = rr & 15;
      float v = ((&l4.x)[j] + (&b4.x)[j]) * SCAL;
      Lsh[((e*NW + wv2)*16 + arr)*8 + n] = (_Float16)v;
    }
  }
  __syncthreads();
  const int lane = tid & 63;
  const int wv   = tid >> 6;
  const int ar   = lane & 15;
  const int kg   = lane >> 4;
  const int wbase = wv * (H_/NW);
  f32x4 acc[8] = {};
  {
    const int a_sw = (ar & 7) << 4;
    #pragma unroll 1
    for (int step = 0; step < H_/32; ++step) {
      int kb = step*64 + kg*16;
      bf16x8 a0 = *(const bf16x8*)(smem + ((ar*1536 + kb) ^ a_sw));
      int k = step*32 + kg*8;
      #pragma unroll
      for (int n = 0; n < 8; ++n) {
        int gcol = wbase + n*16 + ar;
        float4 u = *(const float4*)(attw + (size_t)gcol*H_ + k);
        float4 v = *(const float4*)(attw + (size_t)gcol*H_ + k + 4);
        bf16x8 bb;
        bb[0]=(bf16_t)(u.x*SCAL); bb[1]=(bf16_t)(u.y*SCAL); bb[2]=(bf16_t)(u.z*SCAL); bb[3]=(bf16_t)(u.w*SCAL);
        bb[4]=(bf16_t)(v.x*SCAL); bb[5]=(bf16_t)(v.y*SCAL); bb[6]=(bf16_t)(v.z*SCAL); bb[7]=(bf16_t)(v.w*SCAL);
        acc[n] = __builtin_amdgcn_mfma_f32_16x16x32_bf16(a0, bb, acc[n], 0,0,0);
      }
    }
  }
  __syncthreads();
  float fcv[8];
  #pragma unroll
  for (int n = 0; n < 8; ++n) fcv[n] = fcw[wbase + n*16 + ar];
  {
    const _Float16* Lw = Lsh + (wv*16 + ar)*8;
    #pragma unroll 1
    for (int e = 0; e < E_; ++e) {
      f16x8 lh = *(const f16x8*)(Lw + e*(NW*128));
      float lv[8];
      #pragma unroll
      for (int n = 0; n < 8; ++n) lv[n] = (float)lh[n];
      float s8[4] = {};
      #pragma unroll
      for (int n = 0; n < 8; ++n)
        #pragma unroll
        for (int i = 0; i < 4; ++i) {
          float t = __builtin_amdgcn_exp2f(acc[n][i] + lv[n]);
          s8[i] += fcv[n] * __builtin_amdgcn_rcpf(t + 1.0f);
        }
      #pragma unroll
      for (int off = 1; off < 16; off <<= 1)
        #pragma unroll
        for (int i = 0; i < 4; ++i)
          s8[i] += __shfl_xor(s8[i], off, 64);
      if (ar == 0) {
        #pragma unroll
        for (int i = 0; i < 4; ++i)
          Sp[(wv*BM + kg*4 + i)*20 + e] = s8[i];
      }
    }
  }
  __syncthreads();
  if (tid % 24 == 0) {
    int row = tid / 24;
    float sc2[E_];
    float mx = -1e30f;
    #pragma unroll
    for (int e = 0; e < E_; ++e) {
      float v = 0.f;
      #pragma unroll
      for (int w2 = 0; w2 < NW; ++w2) v += Sp[(w2*BM + row)*20 + e];
      sc2[e] = -2.0f * v;
      mx = fmaxf(mx, sc2[e]);
    }
    float ssum = 0.f;
    #pragma unroll
    for (int e = 0; e < E_; ++e) {
      float p = __builtin_amdgcn_exp2f((sc2[e] - mx) * 1.4426950408889634f);
      sc2[e] = p; ssum += p;
    }
    float rr = __builtin_amdgcn_rcpf(ssum);
    #pragma unroll
    for (int e = 0; e < E_; ++e) Pp[row*20 + e] = sc2[e]*rr;
  }
  __syncthreads();
  {
    const int cg = tid % 96;
    const int rq = tid / 96;
    float o[4][8] = {};
    const f32x4* L4 = (const f32x4*)lab;
    #pragma unroll 1
    for (int e = 0; e < E_; ++e) {
      f32x4 la = L4[e*(H_/4) + cg*2];
      f32x4 lb = L4[e*(H_/4) + cg*2 + 1];
      #pragma unroll
      for (int rr2 = 0; rr2 < 4; ++rr2) {
        float p = Pp[(rq*4 + rr2)*20 + e];
        o[rr2][0] += p*la[0]; o[rr2][1] += p*la[1]; o[rr2][2] += p*la[2]; o[rr2][3] += p*la[3];
        o[rr2][4] += p*lb[0]; o[rr2][5] += p*lb[1]; o[rr2][6] += p*lb[2]; o[rr2][7] += p*lb[3];
      }
    }
    const int cnt = counts[batch];
    #pragma unroll
    for (int rr2 = 0; rr2 < 4; ++rr2) {
      int row = rq*4 + rr2;
      int sp  = s0 + row;
      bool keep = (sp >= T0) && (sp < cnt + T0);
      size_t idx = rowbase + (size_t)row*H_ + cg*8;
      float4 s1 = *(const float4*)(seq + idx);
      float4 s2v = *(const float4*)(seq + idx + 4);
      float4 o1, o2;
      if (keep) { o1 = s1; o2 = s2v; }
      else {
        o1 = make_float4(s1.x + o[rr2][0], s1.y + o[rr2][1], s1.z + o[rr2][2], s1.w + o[rr2][3]);
        o2 = make_float4(s2v.x + o[rr2][4], s2v.y + o[rr2][5], s2v.z + o[rr2][6], s2v.w + o[rr2][7]);
      }
      *(float4*)(out + idx)     = o1;
      *(float4*)(out + idx + 4) = o2;
    }
  }
}

extern "C" void kernel_launch(void* const* d_in, const int* in_sizes, int n_in,
                              void* d_out, int out_size, void* d_ws, size_t ws_size,
                              hipStream_t stream) {
  const float* seq    = (const float*)d_in[0];
  const float* lab    = (const float*)d_in[1];
  const float* attw   = (const float*)d_in[2];
  const float* attb   = (const float*)d_in[3];
  const float* fcw    = (const float*)d_in[4];
  const int*   counts = (const int*)d_in[5];
  float* out = (float*)d_out;

  if (ws_size >= (size_t)WS_NEED) {
    bf16_t* wbf = (bf16_t*)((char*)d_ws + WS_W_OFF);
    f16_t*  pls = (f16_t*)((char*)d_ws + WS_PL_OFF);
    f16_t*  fcg = (f16_t*)((char*)d_ws + WS_FC_OFF);
    f16_t*  pxp = (f16_t*)((char*)d_ws + WS_PX_OFF);
    bf16_t* abf = (ws_size >= (size_t)WS_NEED2)
                ? (bf16_t*)((char*)d_ws + WS_AB_OFF)
                : (bf16_t*)d_out;
    prep_kernel<<<dim3((ROWS*H_/8 + 255)/256), dim3(256), 0, stream>>>(
        attw, lab, attb, fcw, seq, counts, wbf, pls, fcg, abf);
    gemm_xs2<<<dim3((ROWS/G_BM)*(H_/G_BN)), dim3(G_NT), 0, stream>>>(
        abf, counts, wbf, pxp);
    score_ctx<<<dim3(ROWS/K2_R), dim3(256), 0, stream>>>(
        pxp, pls, fcw, seq, lab, counts, out);
  } else {
    ner_fused<<<dim3(ROWS/BM), dim3(NT), 0, stream>>>(seq, lab, attw, attb, fcw, counts, out);
  }
}